// Round 1
// baseline (13001.765 us; speedup 1.0000x reference)
//
#include <hip/hip_runtime.h>
#include <hip/hip_bf16.h>
#include <stdint.h>

#define B_ 128
#define T_ 256
#define S_ 256
#define I_ 512
#define H_ 512

typedef __attribute__((ext_vector_type(8))) short short8;
typedef __attribute__((ext_vector_type(4))) float f32x4;
typedef unsigned short ushort_t;

__device__ __forceinline__ float bf2f(ushort_t u){
  union{ unsigned int i; float f;} v; v.i = ((unsigned int)u)<<16; return v.f;
}
__device__ __forceinline__ ushort_t f2bf(float f){
  union{ unsigned int i; float f;} v; v.f=f;
  unsigned int x=v.i; unsigned int r = x + 0x7fffu + ((x>>16)&1u);
  return (ushort_t)(r>>16);
}
__device__ __forceinline__ float sigm(float x){ return 1.f/(1.f + __expf(-x)); }
__device__ __forceinline__ float tanh_s(float x){
  float a = fabsf(x);
  float e = __expf(-2.f*a);
  float t = (1.f - e)/(1.f + e);
  return x < 0.f ? -t : t;
}

__device__ __forceinline__ f32x4 MFMA16(short8 a, short8 b, f32x4 c){
  typedef __attribute__((ext_vector_type(8))) __bf16 bf16x8;
  return __builtin_amdgcn_mfma_f32_16x16x32_bf16(
      __builtin_bit_cast(bf16x8, a), __builtin_bit_cast(bf16x8, b), c, 0, 0, 0);
}

// ---------------- converts / init ----------------

__global__ void k_cvt_bf16(const float* __restrict__ src, ushort_t* __restrict__ dst, int n){
  int i = (blockIdx.x*blockDim.x + threadIdx.x)*4;
  int stride = gridDim.x*blockDim.x*4;
  for (; i < n; i += stride){
    float4 v = *(const float4*)(src + i);
    ushort4 o; o.x=f2bf(v.x); o.y=f2bf(v.y); o.z=f2bf(v.z); o.w=f2bf(v.w);
    *(ushort4*)(dst + i) = o;
  }
}

// out[j*512+k] = in[k*512+j]
__global__ void k_transpose_512(const float* __restrict__ in, float* __restrict__ out){
  __shared__ float tile[32][33];
  int bx = blockIdx.x*32, by = blockIdx.y*32;
  int tx = threadIdx.x, ty = threadIdx.y; // block (32,8)
  for (int r=0;r<32;r+=8) tile[ty+r][tx] = in[(by+ty+r)*512 + bx+tx];
  __syncthreads();
  for (int r=0;r<32;r+=8) out[(bx+ty+r)*512 + by+tx] = tile[tx][ty+r];
}

__global__ void k_init_state(const float* __restrict__ h0, const float* __restrict__ c0,
                             ushort_t* __restrict__ hb, float* __restrict__ cyb){
  int i = blockIdx.x*blockDim.x + threadIdx.x; // 65536 total
  hb[i] = f2bf(h0[i]);
  cyb[i] = c0[i];
}

// ---------------- big precompute GEMM ----------------
// C[M,N] = A[M,K] @ B[N,K]^T (+ bias0[n]+bias1[n]), A,B fp32 in, C bf16 out.
template<int BIAS>
__global__ __launch_bounds__(256) void k_gemm_bt(
    const float* __restrict__ A, const float* __restrict__ Bm,
    ushort_t* __restrict__ C, int M, int N, int K,
    const float* __restrict__ bias0, const float* __restrict__ bias1){
  __shared__ ushort_t Asm[128][40];
  __shared__ ushort_t Bsm[128][40];
  const int tid = threadIdx.x;
  const int mBase = blockIdx.x*128, nBase = blockIdx.y*128;
  const int l = tid & 63, wv = tid >> 6;
  const int wm = (wv>>1)*64, wn = (wv&1)*64;
  const int lr = l & 15, lq = l >> 4;
  const int srow = tid >> 1, scol = (tid & 1)*16;
  const float* Ap = A + (size_t)(mBase + srow)*K + scol;
  const float* Bp = Bm + (size_t)(nBase + srow)*K + scol;

  f32x4 acc[4][4];
  #pragma unroll
  for (int i=0;i<4;i++)
    #pragma unroll
    for (int j=0;j<4;j++) acc[i][j] = (f32x4)0.f;

  for (int k0 = 0; k0 < K; k0 += 32){
    float4 a0 = *(const float4*)(Ap + k0);
    float4 a1 = *(const float4*)(Ap + k0 + 4);
    float4 a2 = *(const float4*)(Ap + k0 + 8);
    float4 a3 = *(const float4*)(Ap + k0 + 12);
    float4 b0 = *(const float4*)(Bp + k0);
    float4 b1 = *(const float4*)(Bp + k0 + 4);
    float4 b2 = *(const float4*)(Bp + k0 + 8);
    float4 b3 = *(const float4*)(Bp + k0 + 12);
    __syncthreads();
    {
      ushort4 w;
      w.x=f2bf(a0.x); w.y=f2bf(a0.y); w.z=f2bf(a0.z); w.w=f2bf(a0.w);
      *(ushort4*)&Asm[srow][scol+0]  = w;
      w.x=f2bf(a1.x); w.y=f2bf(a1.y); w.z=f2bf(a1.z); w.w=f2bf(a1.w);
      *(ushort4*)&Asm[srow][scol+4]  = w;
      w.x=f2bf(a2.x); w.y=f2bf(a2.y); w.z=f2bf(a2.z); w.w=f2bf(a2.w);
      *(ushort4*)&Asm[srow][scol+8]  = w;
      w.x=f2bf(a3.x); w.y=f2bf(a3.y); w.z=f2bf(a3.z); w.w=f2bf(a3.w);
      *(ushort4*)&Asm[srow][scol+12] = w;
      w.x=f2bf(b0.x); w.y=f2bf(b0.y); w.z=f2bf(b0.z); w.w=f2bf(b0.w);
      *(ushort4*)&Bsm[srow][scol+0]  = w;
      w.x=f2bf(b1.x); w.y=f2bf(b1.y); w.z=f2bf(b1.z); w.w=f2bf(b1.w);
      *(ushort4*)&Bsm[srow][scol+4]  = w;
      w.x=f2bf(b2.x); w.y=f2bf(b2.y); w.z=f2bf(b2.z); w.w=f2bf(b2.w);
      *(ushort4*)&Bsm[srow][scol+8]  = w;
      w.x=f2bf(b3.x); w.y=f2bf(b3.y); w.z=f2bf(b3.z); w.w=f2bf(b3.w);
      *(ushort4*)&Bsm[srow][scol+12] = w;
    }
    __syncthreads();
    short8 aF[4], bF[4];
    #pragma unroll
    for (int i=0;i<4;i++) aF[i] = *(const short8*)&Asm[wm + i*16 + lr][lq*8];
    #pragma unroll
    for (int j=0;j<4;j++) bF[j] = *(const short8*)&Bsm[wn + j*16 + lr][lq*8];
    #pragma unroll
    for (int i=0;i<4;i++)
      #pragma unroll
      for (int j=0;j<4;j++)
        acc[i][j] = MFMA16(aF[i], bF[j], acc[i][j]);
  }

  #pragma unroll
  for (int j=0;j<4;j++){
    int col = nBase + wn + j*16 + lr;
    float bsum = 0.f;
    if (BIAS) bsum = bias0[col] + bias1[col];
    #pragma unroll
    for (int i=0;i<4;i++){
      int row0 = mBase + wm + i*16 + lq*4;
      #pragma unroll
      for (int r=0;r<4;r++){
        C[(size_t)(row0+r)*N + col] = f2bf(acc[i][j][r] + bsum);
      }
    }
  }
}

// ---------------- per-step kernels ----------------

// K1: gates = Xg[:,t,:] + h@Wh^T ; LSTM pointwise -> hy (bf16), cy (fp32, in place)
__global__ __launch_bounds__(256) void k_step_gates(
    const ushort_t* __restrict__ hb, const ushort_t* __restrict__ Whb,
    const ushort_t* __restrict__ Xg, float* __restrict__ cy,
    ushort_t* __restrict__ hyb, int t){
  const int tid = threadIdx.x;
  const int l = tid & 63, wv = tid >> 6;
  const int bm = blockIdx.x >> 3;                 // 0..7 (batch tile of 16)
  const int hc = ((blockIdx.x & 7) << 2) | wv;    // 0..31 (h chunk of 16)
  const int lr = l & 15, lq = l >> 4;

  f32x4 acc[4];
  #pragma unroll
  for (int g=0;g<4;g++) acc[g] = (f32x4)0.f;

  const ushort_t* ap  = hb + (bm*16 + lr)*512 + lq*8;
  const ushort_t* bp0 = Whb + (size_t)(hc*16 + lr)*512 + lq*8;

  #pragma unroll 4
  for (int kk=0; kk<16; kk++){
    short8 aF = *(const short8*)(ap + kk*32);
    #pragma unroll
    for (int g=0; g<4; g++){
      short8 bF = *(const short8*)(bp0 + (size_t)g*262144 + kk*32);
      acc[g] = MFMA16(aF, bF, acc[g]);
    }
  }

  #pragma unroll
  for (int r=0;r<4;r++){
    int b = bm*16 + lq*4 + r;
    int h = hc*16 + lr;
    const ushort_t* xg = Xg + ((size_t)b*T_ + t)*2048 + h;
    float gi = acc[0][r] + bf2f(xg[0]);
    float gf = acc[1][r] + bf2f(xg[512]);
    float gg = acc[2][r] + bf2f(xg[1024]);
    float go = acc[3][r] + bf2f(xg[1536]);
    float co = cy[b*512 + h];
    float cn = sigm(gf)*co + sigm(gi)*tanh_s(gg);
    float hn = sigm(go)*tanh_s(cn);
    cy[b*512 + h] = cn;
    hyb[b*512 + h] = f2bf(hn);
  }
}

// K2: per-b attention: scores via C2 (target GEMM eliminated), softmax, wc
__global__ __launch_bounds__(512) void k_step_attn(
    const ushort_t* __restrict__ hyb, const ushort_t* __restrict__ C2,
    const ushort_t* __restrict__ ctxb, ushort_t* __restrict__ wcb){
  __shared__ float hy_s[512];
  __shared__ float sc[256];
  const int b = blockIdx.x;
  const int tid = threadIdx.x;
  hy_s[tid] = bf2f(hyb[b*512 + tid]);
  __syncthreads();
  const int wv = tid >> 6, l = tid & 63;

  // pass 1: scores
  {
    float hv[8];
    #pragma unroll
    for (int e=0;e<8;e++) hv[e] = hy_s[l*8 + e];
    #pragma unroll 2
    for (int i=0;i<32;i++){
      int s = wv*32 + i;
      short8 cv = *(const short8*)(C2 + ((size_t)s*128 + b)*512 + l*8);
      float d = 0.f;
      #pragma unroll
      for (int e=0;e<8;e++) d += bf2f((ushort_t)cv[e]) * hv[e];
      #pragma unroll
      for (int off=32; off; off>>=1) d += __shfl_xor(d, off);
      if (l == 0) sc[s] = d;
    }
  }
  __syncthreads();

  // softmax (wave 0)
  if (wv == 0){
    float v0=sc[l], v1=sc[l+64], v2=sc[l+128], v3=sc[l+192];
    float m = fmaxf(fmaxf(v0,v1), fmaxf(v2,v3));
    #pragma unroll
    for (int off=32; off; off>>=1) m = fmaxf(m, __shfl_xor(m, off));
    float e0=__expf(v0-m), e1=__expf(v1-m), e2=__expf(v2-m), e3=__expf(v3-m);
    float s4 = (e0+e1)+(e2+e3);
    #pragma unroll
    for (int off=32; off; off>>=1) s4 += __shfl_xor(s4, off);
    float inv = 1.f/s4;
    sc[l]=e0*inv; sc[l+64]=e1*inv; sc[l+128]=e2*inv; sc[l+192]=e3*inv;
  }
  __syncthreads();

  // pass 2: wc[h] = sum_s attn[s]*ctx[s,b,h]
  float a0=0.f, a1=0.f, a2=0.f, a3=0.f;
  const ushort_t* cp = ctxb + (size_t)b*512 + tid;
  #pragma unroll 4
  for (int s=0; s<256; s+=4){
    a0 += sc[s+0] * bf2f(cp[(size_t)(s+0)*65536]);
    a1 += sc[s+1] * bf2f(cp[(size_t)(s+1)*65536]);
    a2 += sc[s+2] * bf2f(cp[(size_t)(s+2)*65536]);
    a3 += sc[s+3] * bf2f(cp[(size_t)(s+3)*65536]);
  }
  wcb[b*512 + tid] = f2bf((a0+a1)+(a2+a3));
}

// K3: h_tilde = tanh(concat(wc,hy) @ W_out^T) -> out[b,t,:], hb (bf16)
__global__ __launch_bounds__(256) void k_step_out(
    const ushort_t* __restrict__ wcb, const ushort_t* __restrict__ hyb,
    const ushort_t* __restrict__ Woutb, float* __restrict__ out,
    ushort_t* __restrict__ hb, int t){
  const int tid = threadIdx.x;
  const int l = tid & 63, wv = tid >> 6;
  const int w = blockIdx.x*4 + wv;   // 0..255
  const int mt = w >> 5, nc = w & 31;
  const int lr = l & 15, lq = l >> 4;

  f32x4 acc = (f32x4)0.f;
  const ushort_t* a0p = wcb + (mt*16 + lr)*512 + lq*8;
  const ushort_t* a1p = hyb + (mt*16 + lr)*512 + lq*8;
  const ushort_t* bp  = Woutb + (size_t)(nc*16 + lr)*1024 + lq*8;

  #pragma unroll 4
  for (int kk=0; kk<16; kk++){
    short8 aF = *(const short8*)(a0p + kk*32);
    short8 bF = *(const short8*)(bp + kk*32);
    acc = MFMA16(aF, bF, acc);
  }
  #pragma unroll 4
  for (int kk=0; kk<16; kk++){
    short8 aF = *(const short8*)(a1p + kk*32);
    short8 bF = *(const short8*)(bp + 512 + kk*32);
    acc = MFMA16(aF, bF, acc);
  }

  #pragma unroll
  for (int r=0;r<4;r++){
    int b = mt*16 + lq*4 + r;
    int h = nc*16 + lr;
    float v = tanh_s(acc[r]);
    out[((size_t)b*T_ + t)*512 + h] = v;
    hb[b*512 + h] = f2bf(v);
  }
}

__global__ void k_finalize(const float* __restrict__ out, const float* __restrict__ cyb,
                           float* __restrict__ hf, float* __restrict__ cf){
  int i = blockIdx.x*blockDim.x + threadIdx.x; // 65536
  int b = i >> 9, h = i & 511;
  hf[i] = out[((size_t)b*T_ + (T_-1))*512 + h];
  cf[i] = cyb[i];
}

// ---------------- host ----------------

extern "C" void kernel_launch(void* const* d_in, const int* in_sizes, int n_in,
                              void* d_out, int out_size, void* d_ws, size_t ws_size,
                              hipStream_t stream){
  const float* x    = (const float*)d_in[0];
  const float* h0   = (const float*)d_in[1];
  const float* c0   = (const float*)d_in[2];
  const float* ctx  = (const float*)d_in[3];
  const float* Wi   = (const float*)d_in[4];
  const float* bi   = (const float*)d_in[5];
  const float* Wh   = (const float*)d_in[6];
  const float* bh   = (const float*)d_in[7];
  const float* Win  = (const float*)d_in[8];
  const float* Wout = (const float*)d_in[9];

  char* ws = (char*)d_ws;
  ushort_t* Xg    = (ushort_t*)(ws);                 // 134217728 B
  ushort_t* C2    = (ushort_t*)(ws + 134217728);     //  33554432 B
  ushort_t* ctxb  = (ushort_t*)(ws + 167772160);     //  33554432 B
  ushort_t* Whb   = (ushort_t*)(ws + 201326592);     //   2097152 B
  ushort_t* Woutb = (ushort_t*)(ws + 203423744);     //   1048576 B
  float*    WinT  = (float*)   (ws + 204472320);     //   1048576 B
  ushort_t* hb    = (ushort_t*)(ws + 205520896);     //    131072 B
  ushort_t* hyb   = (ushort_t*)(ws + 205651968);     //    131072 B
  ushort_t* wcb   = (ushort_t*)(ws + 205783040);     //    131072 B
  float*    cyb   = (float*)   (ws + 205914112);     //    262144 B

  float* out = (float*)d_out;
  float* hf  = out + (size_t)B_*T_*H_;
  float* cf  = hf + (size_t)B_*H_;

  // precompute / converts
  k_cvt_bf16<<<2048, 256, 0, stream>>>(ctx, ctxb, S_*B_*H_);
  k_cvt_bf16<<<512, 256, 0, stream>>>(Wh, Whb, 4*H_*H_);
  k_cvt_bf16<<<256, 256, 0, stream>>>(Wout, Woutb, H_*2*H_);
  k_transpose_512<<<dim3(16,16), dim3(32,8), 0, stream>>>(Win, WinT);
  k_init_state<<<256, 256, 0, stream>>>(h0, c0, hb, cyb);

  // Xg = x @ Wi^T + (bi + bh)   [32768 x 2048], K=512
  k_gemm_bt<1><<<dim3(256,16), 256, 0, stream>>>(x, Wi, Xg, B_*T_, 4*H_, I_, bi, bh);
  // C2 = ctx @ W_in   [32768 x 512], K=512  (B-matrix = W_in^T in [N,K] form)
  k_gemm_bt<0><<<dim3(256,4), 256, 0, stream>>>(ctx, WinT, C2, S_*B_, H_, H_, nullptr, nullptr);

  for (int t = 0; t < T_; t++){
    k_step_gates<<<64, 256, 0, stream>>>(hb, Whb, Xg, cyb, hyb, t);
    k_step_attn<<<128, 512, 0, stream>>>(hyb, C2, ctxb, wcb);
    k_step_out<<<64, 256, 0, stream>>>(wcb, hyb, Woutb, out, hb, t);
  }

  k_finalize<<<256, 256, 0, stream>>>(out, cyb, hf, cf);
}